// Round 16
// baseline (221.353 us; speedup 1.0000x reference)
//
#include <hip/hip_runtime.h>
#include <cstddef>

constexpr int Bn = 16, Dn = 512, Nn = 4096, Kn = 64;
constexpr int Np = 4224;   // padded n-pitch for asT_hi/xbf (ushorts; 8448 B)
constexpr int Dp = 520;    // padded aggp pitch (floats; non-pow2)
constexpr float FEPS = 1e-12f;

typedef __bf16 bf16x8 __attribute__((ext_vector_type(8)));
typedef float f32x4 __attribute__((ext_vector_type(4)));

__device__ __forceinline__ unsigned short bf_bits(__bf16 h) {
  union { __bf16 b; unsigned short u; } c;
  c.b = h;
  return c.u;
}

// ---------------------------------------------------------------------------
// kW: transpose conv_w[K][D] -> wT[D][K] (fp32) for kA's s_load broadcast.
// ---------------------------------------------------------------------------
__global__ __launch_bounds__(256) void kW(const float* __restrict__ w,
                                          float* __restrict__ wT) {
  const int idx = blockIdx.x * 256 + threadIdx.x;  // 32768 total
  const int d = idx >> 6, k = idx & 63;
  wT[idx] = w[k * Dn + d];
}

// ---------------------------------------------------------------------------
// kA: R2's measured-fast scalar-broadcast logits kernel (fp32-exact logits,
// lane = n coalesced x loads, W broadcast via s_load, no main-loop LDS).
// Epilogue writes:
//   asT_hi[b][k][Np] = bf16(softmax * invn)   (R12-validated quantization)
//   massp[b][nt][64] (fp32 exact)
// Main loop also emits xbf[b][d][Np] = bf16(x) — each wave writes the
// d-rows with (d>>2)&3 == wave, so each element is written exactly once.
//   grid 1024: b = bid>>6, nt = bid&63 (64 n). 256 thr = 4 waves; wave -> 16 k.
// ---------------------------------------------------------------------------
__global__ __launch_bounds__(256) void kA(const float* __restrict__ x,
                                          const float* __restrict__ wT,
                                          const float* __restrict__ conv_b,
                                          unsigned short* __restrict__ asT_hi,
                                          unsigned short* __restrict__ xbf,
                                          float* __restrict__ massp) {
  __shared__ float red[4][64];
  const int tid = threadIdx.x;
  const int lane = tid & 63;
  const int w = tid >> 6;
  const int kg0 = __builtin_amdgcn_readfirstlane(w << 4);
  const int b = blockIdx.x >> 6;
  const int nt = blockIdx.x & 63;
  const int n0 = nt << 6;
  const float* xp = x + (size_t)b * Dn * Nn + n0 + lane;
  unsigned short* xbp = xbf + (size_t)b * Dn * Np + n0 + lane;

  float acc[16];
#pragma unroll
  for (int j = 0; j < 16; ++j) acc[j] = 0.f;
  float ss = 0.f;

#pragma unroll 2
  for (int d = 0; d < Dn; d += 4) {
    float xv[4];
#pragma unroll
    for (int i = 0; i < 4; ++i) xv[i] = xp[(size_t)(d + i) * Nn];
    float wv[4][16];
#pragma unroll
    for (int i = 0; i < 4; ++i)
#pragma unroll
      for (int j = 0; j < 16; ++j) wv[i][j] = wT[(d + i) * Kn + kg0 + j];
    if (((d >> 2) & 3) == w) {  // this wave owns these 4 d-rows of xbf
#pragma unroll
      for (int i = 0; i < 4; ++i)
        xbp[(size_t)(d + i) * Np] = bf_bits((__bf16)xv[i]);
    }
#pragma unroll
    for (int i = 0; i < 4; ++i) {
      ss = fmaf(xv[i], xv[i], ss);
#pragma unroll
      for (int j = 0; j < 16; ++j) acc[j] = fmaf(wv[i][j], xv[i], acc[j]);
    }
  }

  // ---- epilogue: invn, logits (fp32 exact), softmax over K ----
  const float iv = 1.f / fmaxf(sqrtf(ss), FEPS);
  float lg[16];
#pragma unroll
  for (int j = 0; j < 16; ++j) lg[j] = fmaf(acc[j], iv, conv_b[kg0 + j]);
  float pmax = lg[0];
#pragma unroll
  for (int j = 1; j < 16; ++j) pmax = fmaxf(pmax, lg[j]);
  red[w][lane] = pmax;
  __syncthreads();
  const float gmax = fmaxf(fmaxf(red[0][lane], red[1][lane]),
                           fmaxf(red[2][lane], red[3][lane]));
  __syncthreads();
  float ex[16];
  float psum = 0.f;
#pragma unroll
  for (int j = 0; j < 16; ++j) {
    ex[j] = expf(lg[j] - gmax);
    psum += ex[j];
  }
  red[w][lane] = psum;
  __syncthreads();
  const float gsum =
      (red[0][lane] + red[1][lane]) + (red[2][lane] + red[3][lane]);
  const float isum = 1.f / gsum;

  unsigned short* ab = asT_hi + (size_t)(b * Kn + kg0) * Np + n0 + lane;
#pragma unroll
  for (int j = 0; j < 16; ++j) {
    const float a = ex[j] * isum;
    ab[(size_t)j * Np] = bf_bits((__bf16)(a * iv));
    float m = a;
#pragma unroll
    for (int off = 1; off < 64; off <<= 1) m += __shfl_xor(m, off);
    if (lane == 0) massp[((b << 6) + nt) * Kn + kg0 + j] = m;
  }
}

// ---------------------------------------------------------------------------
// kB: R5's validated MFMA agg kernel, bf16 inputs (hi-only A = R12-validated
// numerics), direct bf16x8 frag loads (no cvt). Barrier-free.
//   mfma_f32_16x16x32_bf16: M=k, N=d, K=n.
//   A: lane l -> k = kw*16+(l&15), n-elems (l>>4)*8+j   (16B contig)
//   B: lane l -> d = dbase+t*16 (+l&15), n-elems (l>>4)*8+j (16B contig)
//   D: lane l -> col d = l&15, row k = (l>>4)*4+r
// 512 thr = 8 waves: wave -> (kw = w&3: 16 k, dh = w>>2: 64 d).
// grid 512: b = bid>>5, dt = (bid>>3)&3 (128 d), seg = bid&7 (512 n).
// Writes aggp[seg][b][k][Dp].
// ---------------------------------------------------------------------------
__global__ __launch_bounds__(512, 4) void kB(const unsigned short* __restrict__ xbf,
                                             const unsigned short* __restrict__ asT_hi,
                                             float* __restrict__ aggp) {
  const int tid = threadIdx.x;
  const int l = tid & 63;
  const int w = tid >> 6;
  const int kw = w & 3;
  const int dh = w >> 2;
  const int b = blockIdx.x >> 5;
  const int dt = (blockIdx.x >> 3) & 3;
  const int seg = blockIdx.x & 7;
  const int lg = l >> 4;
  const int ll = l & 15;

  const unsigned short* ah =
      asT_hi + ((size_t)b * Kn + kw * 16 + ll) * Np + seg * 512 + lg * 8;
  const int dbase = dt * 128 + dh * 64 + ll;
  const unsigned short* xp =
      xbf + ((size_t)b * Dn + dbase) * Np + seg * 512 + lg * 8;

  f32x4 acc[4];
#pragma unroll
  for (int t = 0; t < 4; ++t) acc[t] = (f32x4){0.f, 0.f, 0.f, 0.f};

#pragma unroll 4
  for (int ns = 0; ns < 512; ns += 32) {
    bf16x8 av = *(const bf16x8*)(ah + ns);
#pragma unroll
    for (int t = 0; t < 4; ++t) {
      bf16x8 bx = *(const bf16x8*)(xp + (size_t)(t * 16) * Np + ns);
      acc[t] = __builtin_amdgcn_mfma_f32_16x16x32_bf16(av, bx, acc[t], 0, 0, 0);
    }
  }

  const int krow = kw * 16 + (lg << 2);
#pragma unroll
  for (int t = 0; t < 4; ++t) {
    const int dcol = dt * 128 + dh * 64 + t * 16 + ll;
    float* op = aggp + (((size_t)(seg * Bn + b)) * Kn + krow) * Dp + dcol;
#pragma unroll
    for (int r = 0; r < 4; ++r) op[(size_t)r * Dp] = acc[t][r];
  }
}

// ---------------------------------------------------------------------------
// kC1: per (b,k): mass from massp (64 n-tiles); vlad = sum(aggp over 8 segs)
// - mass*c; intra-normalize over d.
// ---------------------------------------------------------------------------
__device__ __forceinline__ float blockReduceSum(float v, float* sb) {
#pragma unroll
  for (int off = 32; off > 0; off >>= 1) v += __shfl_down(v, off, 64);
  const int lane = threadIdx.x & 63, w = threadIdx.x >> 6;
  if (lane == 0) sb[w] = v;
  __syncthreads();
  if (threadIdx.x == 0) sb[4] = sb[0] + sb[1] + sb[2] + sb[3];
  __syncthreads();
  return sb[4];
}

__global__ __launch_bounds__(256) void kC1(const float* __restrict__ massp,
                                           const float* __restrict__ aggp,
                                           const float* __restrict__ centroids,
                                           float* __restrict__ out,
                                           float* __restrict__ rowsq) {
  __shared__ float sb[5];
  const int tid = threadIdx.x;
  const int b = blockIdx.x >> 6, k = blockIdx.x & 63;
  float s = 0.f;
  if (tid < 64) s = massp[((b << 6) + tid) * Kn + k];
  const float mass = blockReduceSum(s, sb);
  float v[2];
  float sq = 0.f;
#pragma unroll
  for (int u = 0; u < 2; ++u) {
    const int d = tid + (u << 8);
    float val = -mass * centroids[k * Dn + d];
#pragma unroll
    for (int seg = 0; seg < 8; ++seg)
      val += aggp[(((size_t)(seg * Bn + b)) * Kn + k) * Dp + d];
    v[u] = val;
    sq = fmaf(val, val, sq);
  }
  const float rsq = blockReduceSum(sq, sb);
  const float inv = 1.f / fmaxf(sqrtf(rsq), FEPS);
#pragma unroll
  for (int u = 0; u < 2; ++u)
    out[((size_t)b * Kn + k) * Dn + tid + (u << 8)] = v[u] * inv;
  if (tid == 0) rowsq[b * Kn + k] = rsq * inv * inv;
}

// ---------------------------------------------------------------------------
// kC2: final global L2 norm per batch.
// ---------------------------------------------------------------------------
__global__ __launch_bounds__(256) void kC2(float* __restrict__ out,
                                           const float* __restrict__ rowsq) {
  __shared__ float sg;
  const int b = blockIdx.x, tid = threadIdx.x;
  float v = (tid < 64) ? rowsq[b * Kn + tid] : 0.f;
  if (tid < 64) {
#pragma unroll
    for (int off = 32; off > 0; off >>= 1) v += __shfl_down(v, off, 64);
  }
  if (tid == 0) sg = 1.f / fmaxf(sqrtf(v), FEPS);
  __syncthreads();
  const float inv = sg;
  float* ob = out + (size_t)b * (Kn * Dn);
  for (int t = tid; t < Kn * Dn; t += 256) ob[t] *= inv;
}

// ---------------------------------------------------------------------------
extern "C" void kernel_launch(void* const* d_in, const int* in_sizes, int n_in,
                              void* d_out, int out_size, void* d_ws,
                              size_t ws_size, hipStream_t stream) {
  const float* x = (const float*)d_in[0];
  const float* centroids = (const float*)d_in[1];
  const float* conv_w = (const float*)d_in[2];
  const float* conv_b = (const float*)d_in[3];
  float* out = (float*)d_out;
  float* ws = (float*)d_ws;
  // ws layout (float units):
  //   aggp    [0,         4259840)  8 segs x 16 b x 64 k x Dp(520) f32
  //   asT_hi  [4259840,   6422528)  16 x 64 x Np(4224) bf16
  //   xbf     [6422528,  23724032)  16 x 512 x Np(4224) bf16
  //   wT      [23724032, 23756800)  512 x 64 f32
  //   massp   [23756800, 23822336)  16 b x 64 nt x 64 k
  //   rowsq   [23822336, 23823360)
  float* aggp = ws;
  unsigned short* asT_hi = (unsigned short*)(ws + 4259840);
  unsigned short* xbf = (unsigned short*)(ws + 6422528);
  float* wT = ws + 23724032;
  float* massp = ws + 23756800;
  float* rowsq = ws + 23822336;

  kW<<<128, 256, 0, stream>>>(conv_w, wT);
  kA<<<1024, 256, 0, stream>>>(x, wT, conv_b, asT_hi, xbf, massp);
  kB<<<512, 512, 0, stream>>>(xbf, asT_hi, aggp);
  kC1<<<1024, 256, 0, stream>>>(massp, aggp, centroids, out, rowsq);
  kC2<<<16, 256, 0, stream>>>(out, rowsq);
}

// Round 17
// 125.340 us; speedup vs baseline: 1.7660x; 1.7660x over previous
//
#include <hip/hip_runtime.h>
#include <cstddef>

constexpr int Bn = 16, Dn = 512, Nn = 4096, Kn = 64;
constexpr int PN = 128;            // panel n-size
constexpr int XHD = 240;           // d-rows kept in LDS xhi panel (60 KB)
constexpr int Dp = 520;            // padded aggp pitch (non-pow2)
constexpr float FEPS = 1e-12f;

typedef __bf16 bf16x8 __attribute__((ext_vector_type(8)));
typedef float f32x4 __attribute__((ext_vector_type(4)));

__device__ __forceinline__ unsigned short bf_bits(__bf16 h) {
  union { __bf16 b; unsigned short u; } c;
  c.b = h;
  return c.u;
}

// ---------------------------------------------------------------------------
// kW: split conv_w[K][D] (row-major, d-contiguous) into bf16 hi/lo arrays.
// ---------------------------------------------------------------------------
__global__ __launch_bounds__(256) void kW(const float* __restrict__ w,
                                          unsigned short* __restrict__ w_hi,
                                          unsigned short* __restrict__ w_lo) {
  const int idx = blockIdx.x * 256 + threadIdx.x;  // 32768 total
  const float v = w[idx];
  const __bf16 h = (__bf16)v;          // RNE
  const float r = v - (float)h;
  const __bf16 l = (__bf16)r;
  w_hi[idx] = bf_bits(h);
  w_lo[idx] = bf_bits(l);
}

// ---------------------------------------------------------------------------
// kF v9 = R12's validated kernel reshaped for 2 blocks/CU (the m97 recipe:
// a co-resident block fills each barrier drain):
//   - block = ONE 128-n panel (grid 512 = 2 blocks/CU), 512 thr = 8 waves
//   - xhi LDS panel holds only d<240 (60 KB); phase 2 reads d>=240 from
//     global fp32 + RNE cvt (bit-identical bf16 values, R9-validated path)
//   - LDS total 78.5 KB; __launch_bounds__(512,4) caps VGPR <=128
// Phase-1 math bit-identical to R12 (3-term bf16-split logits, in-register
// softmax). Per-panel aggp partials (32/b), kC1 = R15's (validated).
// ---------------------------------------------------------------------------
__global__ __launch_bounds__(512, 4) void kF(const float* __restrict__ x,
                                             const unsigned short* __restrict__ w_hi,
                                             const unsigned short* __restrict__ w_lo,
                                             const float* __restrict__ conv_b,
                                             float* __restrict__ aggp,
                                             float* __restrict__ massp) {
  __shared__ float xs[PN * 33];             // 16.9 KB staging / as_hi reuse
  __shared__ unsigned short xhi[XHD * PN];  // 60 KB bf16-hi panel (d < 240)
  __shared__ float msum[8][64];
  const int tid = threadIdx.x;
  const int l = tid & 63;
  const int wv = tid >> 6;   // 0..7
  const int ll = l & 15;
  const int lg = l >> 4;
  const int b = blockIdx.x >> 5;
  const int p = blockIdx.x & 31;
  const int n0 = p << 7;
  const int srow = tid >> 4;        // 0..31 (staging row within 32-d chunk)
  const int sc0 = (tid & 15) << 3;  // staging col (8 n per thread)
  const int ncol = (wv << 4) + ll;  // phase-1 n within panel
  const float* xbp = x + (size_t)b * Dn * Nn + n0;

  // =================== Phase 1: logits (validated math) ===================
  f32x4 acc[4];
#pragma unroll
  for (int kt = 0; kt < 4; ++kt) acc[kt] = (f32x4){0.f, 0.f, 0.f, 0.f};
  float ss = 0.f;

  float4 pf0 = *(const float4*)(xbp + (size_t)srow * Nn + sc0);
  float4 pf1 = *(const float4*)(xbp + (size_t)srow * Nn + sc0 + 4);

  for (int dc = 0; dc < Dn; dc += 32) {
    // stage fp32 transposed [n][33] (+ bf16-hi into xhi for d < XHD)
    const float pv[8] = {pf0.x, pf0.y, pf0.z, pf0.w, pf1.x, pf1.y, pf1.z, pf1.w};
#pragma unroll
    for (int j = 0; j < 8; ++j) xs[(sc0 + j) * 33 + srow] = pv[j];
    if (dc + srow < XHD) {
      unsigned short hb[8];
#pragma unroll
      for (int j = 0; j < 8; ++j) hb[j] = bf_bits((__bf16)pv[j]);
      const unsigned byteoff =
          (unsigned)(((dc + srow) * PN + sc0) * 2) ^ ((unsigned)(srow & 7) << 4);
      uint4 hv;
      hv.x = (unsigned)hb[0] | ((unsigned)hb[1] << 16);
      hv.y = (unsigned)hb[2] | ((unsigned)hb[3] << 16);
      hv.z = (unsigned)hb[4] | ((unsigned)hb[5] << 16);
      hv.w = (unsigned)hb[6] | ((unsigned)hb[7] << 16);
      *(uint4*)((char*)xhi + byteoff) = hv;
    }
    if (dc + 32 < Dn) {
      pf0 = *(const float4*)(xbp + (size_t)(dc + 32 + srow) * Nn + sc0);
      pf1 = *(const float4*)(xbp + (size_t)(dc + 32 + srow) * Nn + sc0 + 4);
    }
    asm volatile("s_waitcnt lgkmcnt(0)\ns_barrier" ::: "memory");

    // consume chunk
    float xv[8];
#pragma unroll
    for (int j = 0; j < 8; ++j) xv[j] = xs[ncol * 33 + lg * 8 + j];
    bf16x8 bh, bl;
#pragma unroll
    for (int j = 0; j < 8; ++j) {
      ss = fmaf(xv[j], xv[j], ss);
      const __bf16 h = (__bf16)xv[j];
      bh[j] = h;
      bl[j] = (__bf16)(xv[j] - (float)h);
    }
#pragma unroll
    for (int kt = 0; kt < 4; ++kt) {
      const size_t woff = (size_t)(kt * 16 + ll) * Dn + dc + lg * 8;
      bf16x8 ah = *(const bf16x8*)(w_hi + woff);
      bf16x8 al = *(const bf16x8*)(w_lo + woff);
      acc[kt] = __builtin_amdgcn_mfma_f32_16x16x32_bf16(ah, bh, acc[kt], 0, 0, 0);
      acc[kt] = __builtin_amdgcn_mfma_f32_16x16x32_bf16(ah, bl, acc[kt], 0, 0, 0);
      acc[kt] = __builtin_amdgcn_mfma_f32_16x16x32_bf16(al, bh, acc[kt], 0, 0, 0);
    }
    asm volatile("s_waitcnt lgkmcnt(0)\ns_barrier" ::: "memory");
  }

  // ---- softmax (in-register, validated) ----
  ss += __shfl_xor(ss, 16);
  ss += __shfl_xor(ss, 32);
  const float iv = 1.f / fmaxf(sqrtf(ss), FEPS);
  float lgt[16];
#pragma unroll
  for (int kt = 0; kt < 4; ++kt)
#pragma unroll
    for (int r = 0; r < 4; ++r)
      lgt[kt * 4 + r] = fmaf(acc[kt][r], iv, conv_b[kt * 16 + lg * 4 + r]);
  float pmax = lgt[0];
#pragma unroll
  for (int i = 1; i < 16; ++i) pmax = fmaxf(pmax, lgt[i]);
  pmax = fmaxf(pmax, __shfl_xor(pmax, 16));
  pmax = fmaxf(pmax, __shfl_xor(pmax, 32));
  float ex[16];
  float psum = 0.f;
#pragma unroll
  for (int i = 0; i < 16; ++i) {
    ex[i] = expf(lgt[i] - pmax);
    psum += ex[i];
  }
  psum += __shfl_xor(psum, 16);
  psum += __shfl_xor(psum, 32);
  const float isum = 1.f / psum;

  __syncthreads();  // xs reads done; reuse as as_hi

  unsigned short* as_hi = (unsigned short*)xs;  // [ng16][k64][8] bf16
  const int ngb = (wv << 1) + (ll >> 3);
  const int jj = ll & 7;
#pragma unroll
  for (int i = 0; i < 16; ++i) {
    const int k = (i >> 2) * 16 + lg * 4 + (i & 3);
    const float a = ex[i] * isum;
    as_hi[(ngb * 64 + k) * 8 + jj] = bf_bits((__bf16)(a * iv));
    float m = a;
    m += __shfl_xor(m, 1);
    m += __shfl_xor(m, 2);
    m += __shfl_xor(m, 4);
    m += __shfl_xor(m, 8);
    if (ll == 0) msum[wv][k] = m;
  }
  __syncthreads();
  if (tid < 64) {
    float s = 0.f;
#pragma unroll
    for (int ww = 0; ww < 8; ++ww) s += msum[ww][tid];
    massp[((b << 5) + p) * Kn + tid] = s;
  }

  // =================== Phase 2: agg (LDS for d<240, global else) ===========
  f32x4 acc2[4][4];
#pragma unroll
  for (int kt = 0; kt < 4; ++kt)
#pragma unroll
    for (int dt = 0; dt < 4; ++dt) acc2[kt][dt] = (f32x4){0.f, 0.f, 0.f, 0.f};

  const float* xg = x + (size_t)b * Dn * Nn + n0 + lg * 8;

#pragma unroll
  for (int nc = 0; nc < PN; nc += 32) {
    const int ng = (nc >> 3) + lg;
    bf16x8 af[4];
#pragma unroll
    for (int kt = 0; kt < 4; ++kt)
      af[kt] = *(const bf16x8*)(as_hi + (ng * 64 + kt * 16 + ll) * 8);
#pragma unroll
    for (int dt = 0; dt < 4; ++dt) {
      const int dbase = wv * 64 + dt * 16;
      const int d = dbase + ll;
      bf16x8 bx;
      if (dbase < XHD) {  // whole 16-row tile inside the LDS panel
        const unsigned byteoff =
            (unsigned)((d * PN + nc + lg * 8) * 2) ^ ((unsigned)(d & 7) << 4);
        bx = *(const bf16x8*)((const char*)xhi + byteoff);
      } else {            // re-read fp32 from global (L3-hot), RNE cvt
        const float* xr = xg + (size_t)d * Nn + nc;
        float4 x0 = *(const float4*)(xr);
        float4 x1 = *(const float4*)(xr + 4);
        bx[0] = (__bf16)x0.x; bx[1] = (__bf16)x0.y;
        bx[2] = (__bf16)x0.z; bx[3] = (__bf16)x0.w;
        bx[4] = (__bf16)x1.x; bx[5] = (__bf16)x1.y;
        bx[6] = (__bf16)x1.z; bx[7] = (__bf16)x1.w;
      }
#pragma unroll
      for (int kt = 0; kt < 4; ++kt)
        acc2[kt][dt] = __builtin_amdgcn_mfma_f32_16x16x32_bf16(
            af[kt], bx, acc2[kt][dt], 0, 0, 0);
    }
  }

  // store this panel's partials: aggp[((b*32+p)*64 + k)*Dp + d]
  float* outb = aggp + (size_t)((b << 5) + p) * Kn * Dp;
#pragma unroll
  for (int kt = 0; kt < 4; ++kt)
#pragma unroll
    for (int dt = 0; dt < 4; ++dt) {
      const int krow = kt * 16 + (lg << 2);
      const int dcol = wv * 64 + dt * 16 + ll;
      float* op = outb + (size_t)krow * Dp + dcol;
#pragma unroll
      for (int r = 0; r < 4; ++r) op[(size_t)r * Dp] = acc2[kt][dt][r];
    }
}

// ---------------------------------------------------------------------------
// kC1: per (b,k): mass from massp (32 panels); vlad = sum(aggp over 32
// panels) - mass*c; intra-normalize over d.  (R15-validated)
// ---------------------------------------------------------------------------
__device__ __forceinline__ float blockReduceSum(float v, float* sb) {
#pragma unroll
  for (int off = 32; off > 0; off >>= 1) v += __shfl_down(v, off, 64);
  const int lane = threadIdx.x & 63, w = threadIdx.x >> 6;
  if (lane == 0) sb[w] = v;
  __syncthreads();
  if (threadIdx.x == 0) sb[4] = sb[0] + sb[1] + sb[2] + sb[3];
  __syncthreads();
  return sb[4];
}

__global__ __launch_bounds__(256) void kC1(const float* __restrict__ massp,
                                           const float* __restrict__ aggp,
                                           const float* __restrict__ centroids,
                                           float* __restrict__ out,
                                           float* __restrict__ rowsq) {
  __shared__ float sb[5];
  const int tid = threadIdx.x;
  const int b = blockIdx.x >> 6, k = blockIdx.x & 63;
  float s = 0.f;
  if (tid < 32) s = massp[((b << 5) + tid) * Kn + k];
  const float mass = blockReduceSum(s, sb);
  float v[2];
  float sq = 0.f;
#pragma unroll
  for (int u = 0; u < 2; ++u) {
    const int d = tid + (u << 8);
    float val = -mass * centroids[k * Dn + d];
#pragma unroll 8
    for (int pp = 0; pp < 32; ++pp)
      val += aggp[((size_t)((b << 5) + pp) * Kn + k) * Dp + d];
    v[u] = val;
    sq = fmaf(val, val, sq);
  }
  const float rsq = blockReduceSum(sq, sb);
  const float inv = 1.f / fmaxf(sqrtf(rsq), FEPS);
#pragma unroll
  for (int u = 0; u < 2; ++u)
    out[((size_t)b * Kn + k) * Dn + tid + (u << 8)] = v[u] * inv;
  if (tid == 0) rowsq[b * Kn + k] = rsq * inv * inv;
}

// ---------------------------------------------------------------------------
// kC2: final global L2 norm per batch.
// ---------------------------------------------------------------------------
__global__ __launch_bounds__(256) void kC2(float* __restrict__ out,
                                           const float* __restrict__ rowsq) {
  __shared__ float sg;
  const int b = blockIdx.x, tid = threadIdx.x;
  float v = (tid < 64) ? rowsq[b * Kn + tid] : 0.f;
  if (tid < 64) {
#pragma unroll
    for (int off = 32; off > 0; off >>= 1) v += __shfl_down(v, off, 64);
  }
  if (tid == 0) sg = 1.f / fmaxf(sqrtf(v), FEPS);
  __syncthreads();
  const float inv = sg;
  float* ob = out + (size_t)b * (Kn * Dn);
  for (int t = tid; t < Kn * Dn; t += 256) ob[t] *= inv;
}

// ---------------------------------------------------------------------------
extern "C" void kernel_launch(void* const* d_in, const int* in_sizes, int n_in,
                              void* d_out, int out_size, void* d_ws,
                              size_t ws_size, hipStream_t stream) {
  const float* x = (const float*)d_in[0];
  const float* centroids = (const float*)d_in[1];
  const float* conv_w = (const float*)d_in[2];
  const float* conv_b = (const float*)d_in[3];
  float* out = (float*)d_out;
  float* ws = (float*)d_ws;
  // ws layout (float units):
  //   aggp    [0,        17039360)  16 b x 32 p x 64 k x Dp(520) f32
  //   w_hi    [17039360, 17055744)  64x512 bf16 = 16384 floats
  //   w_lo    [17055744, 17072128)
  //   massp   [17072128, 17104896)  16 b x 32 p x 64 k
  //   rowsq   [17104896, 17105920)
  float* aggp = ws;
  unsigned short* w_hi = (unsigned short*)(ws + 17039360);
  unsigned short* w_lo = (unsigned short*)(ws + 17055744);
  float* massp = ws + 17072128;
  float* rowsq = ws + 17104896;

  kW<<<128, 256, 0, stream>>>(conv_w, w_hi, w_lo);
  kF<<<512, 512, 0, stream>>>(x, w_hi, w_lo, conv_b, aggp, massp);
  kC1<<<1024, 256, 0, stream>>>(massp, aggp, centroids, out, rowsq);
  kC2<<<16, 256, 0, stream>>>(out, rowsq);
}